// Round 11
// baseline (128.137 us; speedup 1.0000x reference)
//
#include <hip/hip_runtime.h>

#define BI 128
#define BH 256
#define MT 32
#define NT 256

using f32x4  = __attribute__((ext_vector_type(4))) float;
using short8 = __attribute__((ext_vector_type(8))) short;

// ---------- bf16 helpers (RNE) ----------
__device__ __forceinline__ unsigned short f2bf(float f) {
  unsigned u = __float_as_uint(f);
  u = (u + 0x7FFFu + ((u >> 16) & 1u)) >> 16;
  return (unsigned short)u;
}
__device__ __forceinline__ float bf2f(unsigned short h) {
  return __uint_as_float(((unsigned)h) << 16);
}
__device__ __forceinline__ float fast_tanh(float v) {
  return 1.f - 2.f / (1.f + __expf(2.f * v));
}
__device__ __forceinline__ float fast_sigmoid(float v) {
  return 1.f / (1.f + __expf(-v));
}

// ---------- weight packing: W (HxK row-major f32) -> bf16 in B-fragment order ----------
__global__ void pack_w(const float* __restrict__ W, unsigned short* __restrict__ dst,
                       int K, int total) {
  int t = blockIdx.x * blockDim.x + threadIdx.x;
  if (t >= total) return;
  int lane = t & 63;
  int tile = t >> 6;
  int KT = K >> 5;
  int nf = tile / KT, kt = tile - nf * KT;
  int n  = nf * 16 + (lane & 15);
  int k0 = kt * 32 + (lane >> 4) * 8;
  const float* src = W + (size_t)n * K + k0;
#pragma unroll
  for (int j = 0; j < 8; ++j) dst[(size_t)t * 8 + j] = f2bf(src[j]);
}

// =============== Kernel A: ha = sigmoid(hidden@attn^T + b) * hidden (PROVEN ~10us) ===============
// LDS: 0: h_bf [32][512B] swz (16384); 16384: ha_bf (16384) = 32768 B.
__global__ __launch_bounds__(NT, 3) void ha_kernel(
    const float* __restrict__ hidden, const float* __restrict__ attn_b,
    const unsigned short* __restrict__ attn_p,
    unsigned short* __restrict__ ha_out) {
  extern __shared__ char smem[];
  const int tid = threadIdx.x;
  const int lane = tid & 63;
  const int wid = tid >> 6;
  const int r0 = blockIdx.x * MT;
  const int lrow = lane & 15;
  const int lk = lane >> 4;

#pragma unroll
  for (int it = 0; it < 8; ++it) {
    int idx4 = it * NT + tid;
    int row = idx4 >> 6;
    int c = idx4 & 63;
    f32x4 v = *(const f32x4*)(hidden + (size_t)(r0 + row) * BH + c * 4);
    unsigned h01 = (unsigned)f2bf(v[0]) | ((unsigned)f2bf(v[1]) << 16);
    unsigned h23 = (unsigned)f2bf(v[2]) | ((unsigned)f2bf(v[3]) << 16);
    *(unsigned long long*)(smem + row * 512 + ((c * 8) ^ ((row & 7) << 4))) =
        (unsigned long long)h01 | ((unsigned long long)h23 << 32);
  }
  __syncthreads();

  f32x4 acc[2][4] = {};
  {
    const short8* bW = (const short8*)attn_p;
#pragma unroll
    for (int kt = 0; kt < 8; ++kt) {
      short8 ah[2];
#pragma unroll
      for (int mf = 0; mf < 2; ++mf) {
        int row = mf * 16 + lrow;
        ah[mf] = *(const short8*)(smem + row * 512 + ((kt * 64 + lk * 16) ^ ((row & 7) << 4)));
      }
#pragma unroll
      for (int nf = 0; nf < 4; ++nf) {
        short8 b = bW[((wid * 4 + nf) * 8 + kt) * 64 + lane];
#pragma unroll
        for (int mf = 0; mf < 2; ++mf)
          acc[mf][nf] = __builtin_amdgcn_mfma_f32_16x16x32_bf16(ah[mf], b, acc[mf][nf], 0, 0, 0);
      }
    }
  }

#pragma unroll
  for (int nf = 0; nf < 4; ++nf) {
    int col = wid * 64 + nf * 16 + lrow;
    float bb = attn_b[col];
#pragma unroll
    for (int mf = 0; mf < 2; ++mf) {
#pragma unroll
      for (int j = 0; j < 4; ++j) {
        int row = mf * 16 + lk * 4 + j;
        float aw = fast_sigmoid(acc[mf][nf][j] + bb);
        int hoff = row * 512 + ((col * 2) ^ ((row & 7) << 4));
        float h = bf2f(*(const unsigned short*)(smem + hoff));
        *(unsigned short*)(smem + 16384 + hoff) = f2bf(h * aw);
      }
    }
  }
  __syncthreads();

#pragma unroll
  for (int p = 0; p < 4; ++p) {
    int c = p * NT + tid;
    int row = c >> 5;
    int cp = (c & 31) * 16;
    f32x4 v = *(const f32x4*)(smem + 16384 + row * 512 + (cp ^ ((row & 7) << 4)));
    *(f32x4*)((char*)ha_out + (size_t)blockIdx.x * 16384 + (size_t)c * 16) = v;
  }
}

// =============== Kernel B: ic = tanh(x@W_in^T + b) -> out body (f32); ew -> out tail ===============
// LDS: ic f32 [32][1024B] swz = 32768 B. ONE acc set, ONE barrier.
__global__ __launch_bounds__(NT, 3) void icew_kernel(
    const float* __restrict__ x, const float* __restrict__ prev,
    const float* __restrict__ w_in_b,
    const float* __restrict__ ev_w, const float* __restrict__ ev_b,
    const unsigned short* __restrict__ win_p,
    float* __restrict__ out, int Bn) {
  extern __shared__ char smem[];
  const int tid = threadIdx.x;
  const int lane = tid & 63;
  const int wid = tid >> 6;
  const int r0 = blockIdx.x * MT;
  const int lrow = lane & 15;
  const int lk = lane >> 4;

  // ---- event weight (independent of GEMM1; no barrier) ----
  {
    int r = tid >> 3, p = tid & 7;
    float s = 0.f;
    const float* src = (p < 4) ? (x + (size_t)(r0 + r) * BI + p * 32)
                               : (prev + (size_t)(r0 + r) * BI + (p - 4) * 32);
    const float* wr = ev_w + p * 32;
#pragma unroll
    for (int i = 0; i < 8; ++i) {
      f32x4 a = *(const f32x4*)(src + i * 4);
      f32x4 w = *(const f32x4*)(wr + i * 4);
      s += a[0] * w[0] + a[1] * w[1] + a[2] * w[2] + a[3] * w[3];
    }
    s += __shfl_xor(s, 1);
    s += __shfl_xor(s, 2);
    s += __shfl_xor(s, 4);
    if (p == 0)
      out[(size_t)Bn * BH + r0 + r] = fast_sigmoid(s + ev_b[0]);
  }

  // ---- GEMM1 ----
  f32x4 ic[2][4] = {};
  {
    const short8* bW = (const short8*)win_p;
#pragma unroll
    for (int kt = 0; kt < 4; ++kt) {
      short8 ax[2];
#pragma unroll
      for (int mf = 0; mf < 2; ++mf) {
        const float* xr = x + (size_t)(r0 + mf * 16 + lrow) * BI + kt * 32 + lk * 8;
        f32x4 a0 = *(const f32x4*)xr;
        f32x4 a1 = *(const f32x4*)(xr + 4);
        short8 t;
        t[0] = (short)f2bf(a0[0]); t[1] = (short)f2bf(a0[1]);
        t[2] = (short)f2bf(a0[2]); t[3] = (short)f2bf(a0[3]);
        t[4] = (short)f2bf(a1[0]); t[5] = (short)f2bf(a1[1]);
        t[6] = (short)f2bf(a1[2]); t[7] = (short)f2bf(a1[3]);
        ax[mf] = t;
      }
#pragma unroll
      for (int nf = 0; nf < 4; ++nf) {
        short8 b = bW[((wid * 4 + nf) * 4 + kt) * 64 + lane];
#pragma unroll
        for (int mf = 0; mf < 2; ++mf)
          ic[mf][nf] = __builtin_amdgcn_mfma_f32_16x16x32_bf16(ax[mf], b, ic[mf][nf], 0, 0, 0);
      }
    }
  }

  // tanh + stash f32 swz
#pragma unroll
  for (int nf = 0; nf < 4; ++nf) {
    int col = wid * 64 + nf * 16 + lrow;
    float bb = w_in_b[col];
#pragma unroll
    for (int mf = 0; mf < 2; ++mf) {
#pragma unroll
      for (int j = 0; j < 4; ++j) {
        int row = mf * 16 + lk * 4 + j;
        *(float*)(smem + row * 1024 + ((col * 4) ^ ((row & 7) << 4))) =
            fast_tanh(ic[mf][nf][j] + bb);
      }
    }
  }
  __syncthreads();

  // coalesced f32 store of ic into OUT BODY (rec_kernel reads then overwrites)
#pragma unroll
  for (int it = 0; it < 8; ++it) {
    int row = it * 4 + wid;
    f32x4 v = *(const f32x4*)(smem + row * 1024 + ((lane * 16) ^ ((row & 7) << 4)));
    *(f32x4*)(out + (size_t)(r0 + row) * BH + lane * 4) = v;
  }
}

// =============== Kernel C: rcc = ha@W_rec^T; out = h + dt/tau*(ic + tanh(rcc+b) - h)*(1+ew) ===============
// LDS: ha_bf [32][512B] swz (16384); s_bf overlaid after barrier. ONE acc set.
__global__ __launch_bounds__(NT, 3) void rec_kernel(
    const float* __restrict__ hidden, const float* __restrict__ w_rec_b,
    const float* __restrict__ tau,
    const unsigned short* __restrict__ wrec_p,
    const unsigned short* __restrict__ ha_in,
    float* __restrict__ out, int Bn) {
  extern __shared__ char smem[];
  const int tid = threadIdx.x;
  const int lane = tid & 63;
  const int wid = tid >> 6;
  const int r0 = blockIdx.x * MT;
  const int lrow = lane & 15;
  const int lk = lane >> 4;

  // stage ha (coalesced ws read -> swz LDS)
#pragma unroll
  for (int p = 0; p < 4; ++p) {
    int c = p * NT + tid;
    int row = c >> 5;
    int cp = (c & 31) * 16;
    f32x4 v = *(const f32x4*)((const char*)ha_in + (size_t)blockIdx.x * 16384 + (size_t)c * 16);
    *(f32x4*)(smem + row * 512 + (cp ^ ((row & 7) << 4))) = v;
  }
  __syncthreads();

  // GEMM3
  f32x4 rcc[2][4] = {};
  {
    const short8* bW = (const short8*)wrec_p;
#pragma unroll
    for (int kt = 0; kt < 8; ++kt) {
      short8 ah[2];
#pragma unroll
      for (int mf = 0; mf < 2; ++mf) {
        int row = mf * 16 + lrow;
        ah[mf] = *(const short8*)(smem + row * 512 + ((kt * 64 + lk * 16) ^ ((row & 7) << 4)));
      }
#pragma unroll
      for (int nf = 0; nf < 4; ++nf) {
        short8 b = bW[((wid * 4 + nf) * 8 + kt) * 64 + lane];
#pragma unroll
        for (int mf = 0; mf < 2; ++mf)
          rcc[mf][nf] = __builtin_amdgcn_mfma_f32_16x16x32_bf16(ah[mf], b, rcc[mf][nf], 0, 0, 0);
      }
    }
  }
  __syncthreads();  // ha fully consumed -> overlay s

  // s = tanh(rcc + b) -> bf16 swz overlay
#pragma unroll
  for (int nf = 0; nf < 4; ++nf) {
    int col = wid * 64 + nf * 16 + lrow;
    float brec = w_rec_b[col];
#pragma unroll
    for (int mf = 0; mf < 2; ++mf) {
#pragma unroll
      for (int j = 0; j < 4; ++j) {
        int row = mf * 16 + lk * 4 + j;
        *(unsigned short*)(smem + row * 512 + ((col * 2) ^ ((row & 7) << 4))) =
            f2bf(fast_tanh(rcc[mf][nf][j] + brec));
      }
    }
  }
  __syncthreads();

  // final coalesced pass
  {
    f32x4 t4 = *(const f32x4*)(tau + lane * 4);
    f32x4 dtt;
#pragma unroll
    for (int i = 0; i < 4; ++i) {
      float t = fminf(fmaxf(t4[i], 0.1f), 10.f);
      dtt[i] = 0.1f / t;
    }
#pragma unroll
    for (int it = 0; it < 8; ++it) {
      int row = it * 4 + wid;
      float e1 = 1.f + out[(size_t)Bn * BH + r0 + row];
      unsigned long long sv = *(const unsigned long long*)(
          smem + row * 512 + ((lane * 8) ^ ((row & 7) << 4)));
      float* orow = out + (size_t)(r0 + row) * BH + lane * 4;
      f32x4 ic4 = *(const f32x4*)orow;                 // ic written by icew_kernel
      f32x4 h4 = *(const f32x4*)(hidden + (size_t)(r0 + row) * BH + lane * 4);
      f32x4 o;
#pragma unroll
      for (int i = 0; i < 4; ++i) {
        float s = bf2f((unsigned short)(sv >> (16 * i)));
        o[i] = h4[i] + dtt[i] * (ic4[i] + s - h4[i]) * e1;
      }
      *(f32x4*)orow = o;
    }
  }
}

extern "C" void kernel_launch(void* const* d_in, const int* in_sizes, int n_in,
                              void* d_out, int out_size, void* d_ws, size_t ws_size,
                              hipStream_t stream) {
  const float* x       = (const float*)d_in[0];
  const float* prev    = (const float*)d_in[1];
  const float* hidden  = (const float*)d_in[2];
  const float* W_in_w  = (const float*)d_in[3];
  const float* W_in_b  = (const float*)d_in[4];
  const float* W_rec_w = (const float*)d_in[5];
  const float* W_rec_b = (const float*)d_in[6];
  const float* attn_w  = (const float*)d_in[7];
  const float* attn_b  = (const float*)d_in[8];
  const float* ev_w    = (const float*)d_in[9];
  const float* ev_b    = (const float*)d_in[10];
  const float* tau     = (const float*)d_in[11];
  int Bn = in_sizes[0] / BI;

  unsigned short* ws = (unsigned short*)d_ws;
  unsigned short* win_p  = ws;             // 32768 elems
  unsigned short* attn_p = ws + 32768;     // 65536 elems
  unsigned short* wrec_p = ws + 98304;     // 65536 elems
  unsigned short* ha_ws  = ws + 163840;    // Bn*BH elems (33.5 MB)

  pack_w<<<(4096 + 255) / 256, 256, 0, stream>>>(W_in_w, win_p, BI, 4096);
  pack_w<<<(8192 + 255) / 256, 256, 0, stream>>>(attn_w, attn_p, BH, 8192);
  pack_w<<<(8192 + 255) / 256, 256, 0, stream>>>(W_rec_w, wrec_p, BH, 8192);

  ha_kernel<<<Bn / MT, NT, 32768, stream>>>(hidden, attn_b, attn_p, ha_ws);

  icew_kernel<<<Bn / MT, NT, 32768, stream>>>(
      x, prev, W_in_b, ev_w, ev_b, win_p, (float*)d_out, Bn);

  rec_kernel<<<Bn / MT, NT, 16384, stream>>>(
      hidden, W_rec_b, tau, wrec_p, ha_ws, (float*)d_out, Bn);
}

// Round 12
// 121.682 us; speedup vs baseline: 1.0530x; 1.0530x over previous
//
#include <hip/hip_runtime.h>

#define BI 128
#define BH 256
#define MT 32
#define NT 256

using f32x4  = __attribute__((ext_vector_type(4))) float;
using short8 = __attribute__((ext_vector_type(8))) short;

// ---------- bf16 helpers (RNE) ----------
__device__ __forceinline__ unsigned short f2bf(float f) {
  unsigned u = __float_as_uint(f);
  u = (u + 0x7FFFu + ((u >> 16) & 1u)) >> 16;
  return (unsigned short)u;
}
__device__ __forceinline__ float bf2f(unsigned short h) {
  return __uint_as_float(((unsigned)h) << 16);
}
__device__ __forceinline__ float fast_tanh(float v) {
  return 1.f - 2.f / (1.f + __expf(2.f * v));
}
__device__ __forceinline__ float fast_sigmoid(float v) {
  return 1.f / (1.f + __expf(-v));
}

// ---------- weight packing: W (HxK row-major f32) -> bf16 in B-fragment order ----------
__global__ void pack_w(const float* __restrict__ W, unsigned short* __restrict__ dst,
                       int K, int total) {
  int t = blockIdx.x * blockDim.x + threadIdx.x;
  if (t >= total) return;
  int lane = t & 63;
  int tile = t >> 6;
  int KT = K >> 5;
  int nf = tile / KT, kt = tile - nf * KT;
  int n  = nf * 16 + (lane & 15);
  int k0 = kt * 32 + (lane >> 4) * 8;
  const float* src = W + (size_t)n * K + k0;
#pragma unroll
  for (int j = 0; j < 8; ++j) dst[(size_t)t * 8 + j] = f2bf(src[j]);
}

// =============== Kernel A: ha = sigmoid(hidden@attn^T + b) * hidden (PROVEN ~10us) ===============
// LDS: 0: h_bf [32][512B] swz (16384); 16384: ha_bf (16384) = 32768 B.
__global__ __launch_bounds__(NT, 3) void ha_kernel(
    const float* __restrict__ hidden, const float* __restrict__ attn_b,
    const unsigned short* __restrict__ attn_p,
    unsigned short* __restrict__ ha_out) {
  extern __shared__ char smem[];
  const int tid = threadIdx.x;
  const int lane = tid & 63;
  const int wid = tid >> 6;
  const int r0 = blockIdx.x * MT;
  const int lrow = lane & 15;
  const int lk = lane >> 4;

#pragma unroll
  for (int it = 0; it < 8; ++it) {
    int idx4 = it * NT + tid;
    int row = idx4 >> 6;
    int c = idx4 & 63;
    f32x4 v = *(const f32x4*)(hidden + (size_t)(r0 + row) * BH + c * 4);
    unsigned h01 = (unsigned)f2bf(v[0]) | ((unsigned)f2bf(v[1]) << 16);
    unsigned h23 = (unsigned)f2bf(v[2]) | ((unsigned)f2bf(v[3]) << 16);
    *(unsigned long long*)(smem + row * 512 + ((c * 8) ^ ((row & 7) << 4))) =
        (unsigned long long)h01 | ((unsigned long long)h23 << 32);
  }
  __syncthreads();

  f32x4 acc[2][4] = {};
  {
    const short8* bW = (const short8*)attn_p;
#pragma unroll
    for (int kt = 0; kt < 8; ++kt) {
      short8 ah[2];
#pragma unroll
      for (int mf = 0; mf < 2; ++mf) {
        int row = mf * 16 + lrow;
        ah[mf] = *(const short8*)(smem + row * 512 + ((kt * 64 + lk * 16) ^ ((row & 7) << 4)));
      }
#pragma unroll
      for (int nf = 0; nf < 4; ++nf) {
        short8 b = bW[((wid * 4 + nf) * 8 + kt) * 64 + lane];
#pragma unroll
        for (int mf = 0; mf < 2; ++mf)
          acc[mf][nf] = __builtin_amdgcn_mfma_f32_16x16x32_bf16(ah[mf], b, acc[mf][nf], 0, 0, 0);
      }
    }
  }

#pragma unroll
  for (int nf = 0; nf < 4; ++nf) {
    int col = wid * 64 + nf * 16 + lrow;
    float bb = attn_b[col];
#pragma unroll
    for (int mf = 0; mf < 2; ++mf) {
#pragma unroll
      for (int j = 0; j < 4; ++j) {
        int row = mf * 16 + lk * 4 + j;
        float aw = fast_sigmoid(acc[mf][nf][j] + bb);
        int hoff = row * 512 + ((col * 2) ^ ((row & 7) << 4));
        float h = bf2f(*(const unsigned short*)(smem + hoff));
        *(unsigned short*)(smem + 16384 + hoff) = f2bf(h * aw);
      }
    }
  }
  __syncthreads();

#pragma unroll
  for (int p = 0; p < 4; ++p) {
    int c = p * NT + tid;
    int row = c >> 5;
    int cp = (c & 31) * 16;
    f32x4 v = *(const f32x4*)(smem + 16384 + row * 512 + (cp ^ ((row & 7) << 4)));
    *(f32x4*)((char*)ha_out + (size_t)blockIdx.x * 16384 + (size_t)c * 16) = v;
  }
}

// =============== Kernel B: ic = tanh(x@W_in^T + b) -> out body (f32); ew -> out tail ===============
// NOW ha-template: x staged into LDS coalesced; GEMM1 A-fragments from LDS.
// LDS: 0: x_bf [32][256B] swz (8192); 8192: ic f32 [32][1024B] swz (32768) = 40960 B.
__global__ __launch_bounds__(NT, 3) void ic_kernel(
    const float* __restrict__ x, const float* __restrict__ prev,
    const float* __restrict__ w_in_b,
    const float* __restrict__ ev_w, const float* __restrict__ ev_b,
    const unsigned short* __restrict__ win_p,
    float* __restrict__ out, int Bn) {
  extern __shared__ char smem[];
  const int tid = threadIdx.x;
  const int lane = tid & 63;
  const int wid = tid >> 6;
  const int r0 = blockIdx.x * MT;
  const int lrow = lane & 15;
  const int lk = lane >> 4;

  // ---- stage x (32x128) -> bf16 swz LDS, fully coalesced ----
#pragma unroll
  for (int it = 0; it < 4; ++it) {
    int idx4 = it * NT + tid;
    int row = idx4 >> 5;
    int c = idx4 & 31;
    f32x4 v = *(const f32x4*)(x + (size_t)(r0 + row) * BI + c * 4);
    unsigned h01 = (unsigned)f2bf(v[0]) | ((unsigned)f2bf(v[1]) << 16);
    unsigned h23 = (unsigned)f2bf(v[2]) | ((unsigned)f2bf(v[3]) << 16);
    *(unsigned long long*)(smem + row * 256 + ((c * 8) ^ ((row & 7) << 4))) =
        (unsigned long long)h01 | ((unsigned long long)h23 << 32);
  }

  // ---- event weight (byte-identical to r11 — isolation control) ----
  {
    int r = tid >> 3, p = tid & 7;
    float s = 0.f;
    const float* src = (p < 4) ? (x + (size_t)(r0 + r) * BI + p * 32)
                               : (prev + (size_t)(r0 + r) * BI + (p - 4) * 32);
    const float* wr = ev_w + p * 32;
#pragma unroll
    for (int i = 0; i < 8; ++i) {
      f32x4 a = *(const f32x4*)(src + i * 4);
      f32x4 w = *(const f32x4*)(wr + i * 4);
      s += a[0] * w[0] + a[1] * w[1] + a[2] * w[2] + a[3] * w[3];
    }
    s += __shfl_xor(s, 1);
    s += __shfl_xor(s, 2);
    s += __shfl_xor(s, 4);
    if (p == 0)
      out[(size_t)Bn * BH + r0 + r] = fast_sigmoid(s + ev_b[0]);
  }
  __syncthreads();

  // ---- GEMM1: A from LDS ----
  f32x4 ic[2][4] = {};
  {
    const short8* bW = (const short8*)win_p;
#pragma unroll
    for (int kt = 0; kt < 4; ++kt) {
      short8 ax[2];
#pragma unroll
      for (int mf = 0; mf < 2; ++mf) {
        int row = mf * 16 + lrow;
        ax[mf] = *(const short8*)(smem + row * 256 + ((kt * 64 + lk * 16) ^ ((row & 7) << 4)));
      }
#pragma unroll
      for (int nf = 0; nf < 4; ++nf) {
        short8 b = bW[((wid * 4 + nf) * 4 + kt) * 64 + lane];
#pragma unroll
        for (int mf = 0; mf < 2; ++mf)
          ic[mf][nf] = __builtin_amdgcn_mfma_f32_16x16x32_bf16(ax[mf], b, ic[mf][nf], 0, 0, 0);
      }
    }
  }

  // ---- tanh -> f32 swz stash ----
#pragma unroll
  for (int nf = 0; nf < 4; ++nf) {
    int col = wid * 64 + nf * 16 + lrow;
    float bb = w_in_b[col];
#pragma unroll
    for (int mf = 0; mf < 2; ++mf) {
#pragma unroll
      for (int j = 0; j < 4; ++j) {
        int row = mf * 16 + lk * 4 + j;
        *(float*)(smem + 8192 + row * 1024 + ((col * 4) ^ ((row & 7) << 4))) =
            fast_tanh(ic[mf][nf][j] + bb);
      }
    }
  }
  __syncthreads();

  // ---- coalesced f32 store of ic into OUT BODY (rec_kernel reads then overwrites) ----
#pragma unroll
  for (int it = 0; it < 8; ++it) {
    int row = it * 4 + wid;
    f32x4 v = *(const f32x4*)(smem + 8192 + row * 1024 + ((lane * 16) ^ ((row & 7) << 4)));
    *(f32x4*)(out + (size_t)(r0 + row) * BH + lane * 4) = v;
  }
}

// =============== Kernel C: rcc = ha@W_rec^T; out = h + dt/tau*(ic + tanh(rcc+b) - h)*(1+ew) ===============
// LDS: 0: ha_bf [32][512B] swz (16384); 16384: s f32 [32][1024B] swz (32768) = 49152 B.
__global__ __launch_bounds__(NT, 3) void rec_kernel(
    const float* __restrict__ hidden, const float* __restrict__ w_rec_b,
    const float* __restrict__ tau,
    const unsigned short* __restrict__ wrec_p,
    const unsigned short* __restrict__ ha_in,
    float* __restrict__ out, int Bn) {
  extern __shared__ char smem[];
  const int tid = threadIdx.x;
  const int lane = tid & 63;
  const int wid = tid >> 6;
  const int r0 = blockIdx.x * MT;
  const int lrow = lane & 15;
  const int lk = lane >> 4;

  // stage ha (coalesced ws read -> swz LDS)
#pragma unroll
  for (int p = 0; p < 4; ++p) {
    int c = p * NT + tid;
    int row = c >> 5;
    int cp = (c & 31) * 16;
    f32x4 v = *(const f32x4*)((const char*)ha_in + (size_t)blockIdx.x * 16384 + (size_t)c * 16);
    *(f32x4*)(smem + row * 512 + (cp ^ ((row & 7) << 4))) = v;
  }
  __syncthreads();

  // GEMM3
  f32x4 rcc[2][4] = {};
  {
    const short8* bW = (const short8*)wrec_p;
#pragma unroll
    for (int kt = 0; kt < 8; ++kt) {
      short8 ah[2];
#pragma unroll
      for (int mf = 0; mf < 2; ++mf) {
        int row = mf * 16 + lrow;
        ah[mf] = *(const short8*)(smem + row * 512 + ((kt * 64 + lk * 16) ^ ((row & 7) << 4)));
      }
#pragma unroll
      for (int nf = 0; nf < 4; ++nf) {
        short8 b = bW[((wid * 4 + nf) * 8 + kt) * 64 + lane];
#pragma unroll
        for (int mf = 0; mf < 2; ++mf)
          rcc[mf][nf] = __builtin_amdgcn_mfma_f32_16x16x32_bf16(ah[mf], b, rcc[mf][nf], 0, 0, 0);
      }
    }
  }

  // s = tanh(rcc + b) -> f32 swz region (separate from ha; no extra barrier needed)
#pragma unroll
  for (int nf = 0; nf < 4; ++nf) {
    int col = wid * 64 + nf * 16 + lrow;
    float brec = w_rec_b[col];
#pragma unroll
    for (int mf = 0; mf < 2; ++mf) {
#pragma unroll
      for (int j = 0; j < 4; ++j) {
        int row = mf * 16 + lk * 4 + j;
        *(float*)(smem + 16384 + row * 1024 + ((col * 4) ^ ((row & 7) << 4))) =
            fast_tanh(rcc[mf][nf][j] + brec);
      }
    }
  }
  __syncthreads();

  // final coalesced pass
  {
    f32x4 t4 = *(const f32x4*)(tau + lane * 4);
    f32x4 dtt;
#pragma unroll
    for (int i = 0; i < 4; ++i) {
      float t = fminf(fmaxf(t4[i], 0.1f), 10.f);
      dtt[i] = 0.1f / t;
    }
#pragma unroll
    for (int it = 0; it < 8; ++it) {
      int row = it * 4 + wid;
      float e1 = 1.f + out[(size_t)Bn * BH + r0 + row];
      f32x4 s4 = *(const f32x4*)(smem + 16384 + row * 1024 + ((lane * 16) ^ ((row & 7) << 4)));
      float* orow = out + (size_t)(r0 + row) * BH + lane * 4;
      f32x4 ic4 = *(const f32x4*)orow;                 // ic written by ic_kernel
      f32x4 h4 = *(const f32x4*)(hidden + (size_t)(r0 + row) * BH + lane * 4);
      f32x4 o;
#pragma unroll
      for (int i = 0; i < 4; ++i)
        o[i] = h4[i] + dtt[i] * (ic4[i] + s4[i] - h4[i]) * e1;
      *(f32x4*)orow = o;
    }
  }
}

extern "C" void kernel_launch(void* const* d_in, const int* in_sizes, int n_in,
                              void* d_out, int out_size, void* d_ws, size_t ws_size,
                              hipStream_t stream) {
  const float* x       = (const float*)d_in[0];
  const float* prev    = (const float*)d_in[1];
  const float* hidden  = (const float*)d_in[2];
  const float* W_in_w  = (const float*)d_in[3];
  const float* W_in_b  = (const float*)d_in[4];
  const float* W_rec_w = (const float*)d_in[5];
  const float* W_rec_b = (const float*)d_in[6];
  const float* attn_w  = (const float*)d_in[7];
  const float* attn_b  = (const float*)d_in[8];
  const float* ev_w    = (const float*)d_in[9];
  const float* ev_b    = (const float*)d_in[10];
  const float* tau     = (const float*)d_in[11];
  int Bn = in_sizes[0] / BI;

  unsigned short* ws = (unsigned short*)d_ws;
  unsigned short* win_p  = ws;             // 32768 elems
  unsigned short* attn_p = ws + 32768;     // 65536 elems
  unsigned short* wrec_p = ws + 98304;     // 65536 elems
  unsigned short* ha_ws  = ws + 163840;    // Bn*BH elems (33.5 MB)

  pack_w<<<(4096 + 255) / 256, 256, 0, stream>>>(W_in_w, win_p, BI, 4096);
  pack_w<<<(8192 + 255) / 256, 256, 0, stream>>>(attn_w, attn_p, BH, 8192);
  pack_w<<<(8192 + 255) / 256, 256, 0, stream>>>(W_rec_w, wrec_p, BH, 8192);

  ha_kernel<<<Bn / MT, NT, 32768, stream>>>(hidden, attn_b, attn_p, ha_ws);

  ic_kernel<<<Bn / MT, NT, 40960, stream>>>(
      x, prev, W_in_b, ev_w, ev_b, win_p, (float*)d_out, Bn);

  rec_kernel<<<Bn / MT, NT, 49152, stream>>>(
      hidden, W_rec_b, tau, wrec_p, ha_ws, (float*)d_out, Bn);
}